// Round 9
// baseline (313.431 us; speedup 1.0000x reference)
//
#include <hip/hip_runtime.h>

typedef _Float16 f16;
typedef _Float16 f16x8 __attribute__((ext_vector_type(8)));
typedef _Float16 f16x4 __attribute__((ext_vector_type(4)));
typedef float f32x4 __attribute__((ext_vector_type(4)));

#define GDIM 52
#define GG 2704          // 52*52
#define CIN 256
#define CMID 512
#define COUT 75
#define NIMG 16
#define SPT 192          // conv1 spatial tile
#define NSPB 15          // ceil(2704/192)
#define PH 60            // padded rows in x16p
#define PW 54            // padded cols

#define SLAB_SZ 24576    // one slab buffer (7x54 rows x 32ci x f16, 384-pix slots)

#define VMCNT0 asm volatile("s_waitcnt vmcnt(0)" ::: "memory")

__device__ __forceinline__ float sigmoidf_(float x) {
    return 1.0f / (1.0f + __expf(-x));
}

__device__ __forceinline__ void gload16(const void* g, void* l) {
    __builtin_amdgcn_global_load_lds(
        (const __attribute__((address_space(1))) unsigned int*)g,
        (__attribute__((address_space(3))) unsigned int*)l, 16, 0, 0);
}

// ---- zero the pad borders of x16p (rows 0,53..59 fully; cols 0,53 rows 1..52) ----
__global__ __launch_bounds__(256) void k_zero_border(f16* __restrict__ x16p) {
    int ic = blockIdx.x;             // img*8 + ck
    int tid = threadIdx.x;
    f16x8 z;
#pragma unroll
    for (int k = 0; k < 8; ++k) z[k] = (f16)0;
    for (int j = tid; j < 536; j += 256) {
        int row, col;
        if (j < 432) { int r = j / 54; row = (r == 0) ? 0 : 52 + r; col = j % 54; }
        else { int k = j - 432; row = 1 + (k >> 1); col = (k & 1) * 53; }
        f16* p = x16p + (((size_t)ic * PH + row) * PW + col) * 32;
#pragma unroll
        for (int q = 0; q < 4; ++q) *(f16x8*)(p + q * 8) = z;
    }
}

// ---- prep: x [img][ci][hw] f32 -> x16p [img][ck][h+1][w+1][32ci] f16 (padded) ----
__global__ __launch_bounds__(256) void k_prep_x(const float* __restrict__ x,
                                                f16* __restrict__ x16p) {
    __shared__ float ls[32][133];
    int hw0 = blockIdx.x * 128, ck = blockIdx.y, img = blockIdx.z;
    int tid = threadIdx.x;
    const float* xb = x + ((size_t)img * CIN + ck * 32) * GG;
#pragma unroll
    for (int i = 0; i < 16; ++i) {
        int idx = tid + i * 256;
        int r = idx >> 7, c = idx & 127;
        int hw = hw0 + c;
        ls[r][c] = (hw < GG) ? xb[(size_t)r * GG + hw] : 0.0f;
    }
    __syncthreads();
    int col = tid >> 1, half = tid & 1;
    int hw = hw0 + col;
    if (hw < GG) {
        int h = hw / GDIM, w = hw % GDIM;
        f16* dst = x16p + ((((size_t)img * 8 + ck) * PH + h + 1) * PW + (w + 1)) * 32 + half * 16;
        f16x8 o0, o1;
#pragma unroll
        for (int j = 0; j < 8; ++j) o0[j] = (f16)ls[half * 16 + j][col];
#pragma unroll
        for (int j = 0; j < 8; ++j) o1[j] = (f16)ls[half * 16 + 8 + j][col];
        *(f16x8*)dst = o0;
        *(f16x8*)(dst + 8) = o1;
    }
}

// ---- prep: weights + BN fold.  w16 layout [tap][ck][co][32ci] ----
__global__ __launch_bounds__(256) void k_prep_w(
    const float* __restrict__ w1, const float* __restrict__ w2,
    const float* __restrict__ gamma, const float* __restrict__ beta,
    const float* __restrict__ mean, const float* __restrict__ var,
    f16* __restrict__ w16, f16* __restrict__ w2_16,
    float* __restrict__ bnscale, float* __restrict__ bnshift) {
    int i = blockIdx.x * 256 + threadIdx.x;   // exactly 9*8*512*32 = 1,179,648 threads
    int cl = i & 31;
    int co = (i >> 5) & 511;
    int ckt = i >> 14;          // tap*8 + ck
    int ck = ckt & 7, tap = ckt >> 3;
    int ci = ck * 32 + cl;
    w16[i] = (f16)w1[(size_t)co * 2304 + ci * 9 + tap];
    if (i < COUT * CMID) w2_16[i] = (f16)w2[i];
    if (i < CMID) {
        float s = gamma[i] * rsqrtf(var[i] + 1e-5f);
        bnscale[i] = s;
        bnshift[i] = beta[i] - mean[i] * s;
    }
}

// tap pixel delta (f16 units) for tap literal T
#define TPX(T) ((((T) / 3 - 1) * PW + ((T) % 3) - 1) * 8)

// load A-frags (global, register prefetch) for (TAPN, CKE) into named set aa
#define LDA(aa, TAPN, CKE)                                                     \
    do {                                                                       \
        const f16* ap_ = wAfrag + ((size_t)((TAPN) * 8 + (CKE))) * 16384;      \
        aa##0 = *(const f16x8*)(ap_);                                          \
        aa##1 = *(const f16x8*)(ap_ + 512);                                    \
        aa##2 = *(const f16x8*)(ap_ + 1024);                                   \
        aa##3 = *(const f16x8*)(ap_ + 1536);                                   \
    } while (0)

// read B-frags (LDS) for tap literal TAPC into named set bb
#define LDB(bb, TAPC)                                                          \
    do {                                                                       \
        bb##0 = *(const f16x8*)(Sb + kgx + roff[0] + TPX(TAPC));               \
        bb##1 = *(const f16x8*)(Sb + kgx + roff[1] + TPX(TAPC));               \
        bb##2 = *(const f16x8*)(Sb + kgx + roff[2] + TPX(TAPC));               \
        bb##3 = *(const f16x8*)(Sb + kgx + roff[3] + TPX(TAPC));               \
        bb##4 = *(const f16x8*)(Sb + kgx + roff[4] + TPX(TAPC));               \
        bb##5 = *(const f16x8*)(Sb + kgx + roff[5] + TPX(TAPC));               \
    } while (0)

#define MM1(aa, bb, NF)                                                        \
    do {                                                                       \
        acc[0][NF] = __builtin_amdgcn_mfma_f32_16x16x32_f16(aa##0, bb##NF, acc[0][NF], 0, 0, 0); \
        acc[1][NF] = __builtin_amdgcn_mfma_f32_16x16x32_f16(aa##1, bb##NF, acc[1][NF], 0, 0, 0); \
        acc[2][NF] = __builtin_amdgcn_mfma_f32_16x16x32_f16(aa##2, bb##NF, acc[2][NF], 0, 0, 0); \
        acc[3][NF] = __builtin_amdgcn_mfma_f32_16x16x32_f16(aa##3, bb##NF, acc[3][NF], 0, 0, 0); \
    } while (0)

#define MM(aa, bb)                                                             \
    do {                                                                       \
        MM1(aa, bb, 0); MM1(aa, bb, 1); MM1(aa, bb, 2);                        \
        MM1(aa, bb, 3); MM1(aa, bb, 4); MM1(aa, bb, 5);                        \
    } while (0)

#define SB0 __builtin_amdgcn_sched_barrier(0)

// one ck: 9 taps, software-pipelined. AC/BC = current parity sets, AN/BN = next.
// Entry invariant: A(tap0,ck) already in AC (loaded during prev ck's tap8).
#define CKBODY(AC, AN, BC, BN)                                                 \
    do {                                                                       \
        LDB(BC, 0); SB0;                                                       \
        LDA(AN, 1, ck);  LDB(BN, 1); MM(AC, BC); SB0;                          \
        LDA(AC, 2, ck);  LDB(BC, 2); MM(AN, BN); SB0;                          \
        LDA(AN, 3, ck);  LDB(BN, 3); MM(AC, BC); SB0;                          \
        LDA(AC, 4, ck);  LDB(BC, 4); MM(AN, BN); SB0;                          \
        LDA(AN, 5, ck);  LDB(BN, 5); MM(AC, BC); SB0;                          \
        LDA(AC, 6, ck);  LDB(BC, 6); MM(AN, BN); SB0;                          \
        LDA(AN, 7, ck);  LDB(BN, 7); MM(AC, BC); SB0;                          \
        LDA(AC, 8, ck);  LDB(BC, 8); MM(AN, BN); SB0;                          \
        LDA(AN, 0, ckn); MM(AC, BC); SB0;                                      \
    } while (0)

// ---- conv1: 3x3 + BN + LeakyReLU -> y16 [half][img][n][256co] ----
// 512 thr / 8 waves (4 wm x 2 wn); block 256co x 192sp; wave 64co x 96sp.
// A-frags: global->register, prefetched 1 tap ahead (L2-resident weights).
// B-frags: LDS slab, double-buffered per ck; 1 barrier + 1 vmcnt(0) per ck.
__global__ __launch_bounds__(512, 2) void k_conv1(
    const f16* __restrict__ x16p, const f16* __restrict__ w16,
    const float* __restrict__ bnscale, const float* __restrict__ bnshift,
    f16* __restrict__ y16) {
    __shared__ __align__(16) char smem[101376];   // slab dbuf (49152) / epilogue tb
    int img = blockIdx.x / NSPB, sb = blockIdx.x % NSPB;
    int n0 = sb * SPT;
    int h_lo = n0 / GDIM;
    int half = blockIdx.y;
    int co0 = half * 256;
    int tid = threadIdx.x;
    int lane = tid & 63, wave = tid >> 6;
    int wm = wave >> 1, wn = wave & 1;
    int l15 = lane & 15, kg = lane >> 4;
    int kgx = kg * 3072;                            // f16 units: kg slot in slab

    int roff[6];
#pragma unroll
    for (int nf = 0; nf < 6; ++nf) {
        int n = n0 + wn * 96 + nf * 16 + l15;
        int nc = n < GG ? n : GG - 1;
        int hh = nc / GDIM, ww = nc % GDIM;
        roff[nf] = ((hh - h_lo + 1) * PW + (ww + 1)) * 8;
    }

    f32x4 acc[4][6];
#pragma unroll
    for (int a = 0; a < 4; ++a)
#pragma unroll
        for (int b = 0; b < 6; ++b) {
            acc[a][b][0] = 0.f; acc[a][b][1] = 0.f;
            acc[a][b][2] = 0.f; acc[a][b][3] = 0.f;
        }

    const f16* xbase = x16p + ((size_t)img * 8 * PH + h_lo) * (PW * 32);
    const f16* wAfrag = w16 + (size_t)co0 * 32 + (wm * 64 + l15) * 32 + kg * 8;
    f16x8 Ae_0, Ae_1, Ae_2, Ae_3, Ao_0, Ao_1, Ao_2, Ao_3;
    f16x8 Be_0, Be_1, Be_2, Be_3, Be_4, Be_5;
    f16x8 Bo_0, Bo_1, Bo_2, Bo_3, Bo_4, Bo_5;

    // ---- prologue: issue slab(0) DMA; load A(tap0,ck0) into Ae ----
    {
        f16* sd = (f16*)smem;
#pragma unroll
        for (int p = 0; p < 3; ++p) {
            int c = p * 512 + tid;
            int s = c / 384, pix = c % 384;
            gload16(xbase + (size_t)pix * 32 + s * 8, sd + (size_t)c * 8);
        }
        LDA(Ae_, 0, 0);
    }

    for (int ck = 0; ck < 8; ++ck) {
        VMCNT0;                       // slab(ck) DMA done (issued a full ck ago)
        __builtin_amdgcn_s_barrier();
        SB0;
        if (ck < 7) {                 // issue slab(ck+1) into the other buffer
            const f16* sg = xbase + (size_t)(ck + 1) * (PH * PW * 32);
            f16* sd = (f16*)(smem + ((ck + 1) & 1) * SLAB_SZ);
#pragma unroll
            for (int p = 0; p < 3; ++p) {
                int c = p * 512 + tid;
                int s = c / 384, pix = c % 384;
                gload16(sg + (size_t)pix * 32 + s * 8, sd + (size_t)c * 8);
            }
        }
        SB0;
        const f16* Sb = (const f16*)(smem + (ck & 1) * SLAB_SZ);
        const int ckn = (ck < 7) ? ck + 1 : 7;
        if (!(ck & 1)) {
            CKBODY(Ae_, Ao_, Be_, Bo_);
        } else {
            CKBODY(Ao_, Ae_, Bo_, Be_);
        }
    }
    // ---- epilogue: BN + leaky -> LDS transpose (stride 264 f16) -> linear y16 ----
    VMCNT0;
    __syncthreads();
    f16* tb = (f16*)smem;
#pragma unroll
    for (int mf = 0; mf < 4; ++mf) {
        int cr = wm * 64 + mf * 16 + kg * 4;
        f32x4 sc = *(const f32x4*)(bnscale + co0 + cr);
        f32x4 sh = *(const f32x4*)(bnshift + co0 + cr);
#pragma unroll
        for (int nf = 0; nf < 6; ++nf) {
            int pl = wn * 96 + nf * 16 + l15;
            f16x4 o;
#pragma unroll
            for (int i = 0; i < 4; ++i) {
                float v = acc[mf][nf][i] * sc[i] + sh[i];
                o[i] = (f16)(v > 0.f ? v : 0.1f * v);
            }
            *(f16x4*)(tb + pl * 264 + cr) = o;
        }
    }
    __syncthreads();
    int valid = GG - n0; if (valid > SPT) valid = SPT;
    f16* yb = y16 + (size_t)half * (NIMG * (size_t)GG * 256) + ((size_t)img * GG + n0) * 256;
#pragma unroll
    for (int p = 0; p < 12; ++p) {
        int u = p * 512 + tid, pl = u >> 5, slot = u & 31;
        if (pl < valid)
            *(f16x8*)(yb + (size_t)pl * 256 + slot * 8) =
                *(const f16x8*)(tb + pl * 264 + slot * 8);
    }
}

// ---- conv2 (1x1, K=512) + bias + YOLO decode. 256 thr / 4 waves, 128 n per block ----
__global__ __launch_bounds__(256) void k_conv2(
    const f16* __restrict__ y16, const f16* __restrict__ w2_16,
    const float* __restrict__ b2, float* __restrict__ out) {
    __shared__ float ct[128][81];   // 41472 B
    int img = blockIdx.x / 22, nb = blockIdx.x % 22;
    int n0 = nb * 128;
    int tid = threadIdx.x;
    int lane = tid & 63, wave = tid >> 6;
    int l15 = lane & 15, kg = lane >> 4;

    f32x4 acc[5][2];
#pragma unroll
    for (int a = 0; a < 5; ++a)
#pragma unroll
        for (int b = 0; b < 2; ++b) {
            acc[a][b][0] = 0.f; acc[a][b][1] = 0.f;
            acc[a][b][2] = 0.f; acc[a][b][3] = 0.f;
        }

    int nn[2];
#pragma unroll
    for (int nf = 0; nf < 2; ++nf) {
        int n = n0 + wave * 32 + nf * 16 + l15;
        nn[nf] = n < GG ? n : GG - 1;
    }
    for (int c0 = 0; c0 < CMID; c0 += 32) {
        const f16* yb = y16 + (size_t)(c0 >> 8) * (NIMG * (size_t)GG * 256) +
                        (size_t)img * GG * 256;
        int c = c0 & 255;
        f16x8 af[5];
#pragma unroll
        for (int mf = 0; mf < 5; ++mf) {
            int co = mf * 16 + l15;
            if (co < COUT)
                af[mf] = *(const f16x8*)(w2_16 + (size_t)co * CMID + c0 + kg * 8);
            else {
#pragma unroll
                for (int k = 0; k < 8; ++k) af[mf][k] = (f16)0;
            }
        }
#pragma unroll
        for (int nf = 0; nf < 2; ++nf) {
            f16x8 bf = *(const f16x8*)(yb + (size_t)nn[nf] * 256 + c + kg * 8);
#pragma unroll
            for (int mf = 0; mf < 5; ++mf)
                acc[mf][nf] = __builtin_amdgcn_mfma_f32_16x16x32_f16(
                    af[mf], bf, acc[mf][nf], 0, 0, 0);
        }
    }
#pragma unroll
    for (int mf = 0; mf < 5; ++mf)
#pragma unroll
        for (int nf = 0; nf < 2; ++nf)
            *(f32x4*)(&ct[wave * 32 + nf * 16 + l15][mf * 16 + kg * 4]) = acc[mf][nf];
    __syncthreads();
    // decode: 384 (anchor, n) items over 256 threads
    for (int j = tid; j < 384; j += 256) {
        int a = j >> 7, nl = j & 127;
        int n = n0 + nl;
        if (n >= GG) continue;
        const float* t = &ct[nl][a * 25];
        float tv[25];
#pragma unroll
        for (int q = 0; q < 25; ++q) tv[q] = t[q] + b2[a * 25 + q];
        int h = n / GDIM, w = n % GDIM;
        const float AW[3] = {10.f, 16.f, 33.f};
        const float AH[3] = {13.f, 30.f, 23.f};
        float bx = (sigmoidf_(tv[0]) + (float)w) * 8.0f;
        float by = (sigmoidf_(tv[1]) + (float)h) * 8.0f;
        float bw_ = __expf(tv[2]) * AW[a];
        float bh_ = __expf(tv[3]) * AH[a];
        float* o = out + ((size_t)img * 8112 + (size_t)a * GG + n) * 25;
        o[0] = bx; o[1] = by; o[2] = bw_; o[3] = bh_;
        o[4] = sigmoidf_(tv[4]);
#pragma unroll
        for (int q = 0; q < 20; ++q) o[5 + q] = sigmoidf_(tv[5 + q]);
    }
}

extern "C" void kernel_launch(void* const* d_in, const int* in_sizes, int n_in,
                              void* d_out, int out_size, void* d_ws, size_t ws_size,
                              hipStream_t stream) {
    (void)in_sizes; (void)n_in; (void)out_size; (void)ws_size;
    const float* x     = (const float*)d_in[0];
    const float* w1    = (const float*)d_in[1];
    const float* gamma = (const float*)d_in[2];
    const float* beta  = (const float*)d_in[3];
    const float* mean  = (const float*)d_in[4];
    const float* var   = (const float*)d_in[5];
    const float* w2    = (const float*)d_in[6];
    const float* b2    = (const float*)d_in[7];
    float* out = (float*)d_out;

    char* ws = (char*)d_ws;
    // x16p: 16*8*60*54*32*2 = 26,542,080 B
    f16* x16p     = (f16*)(ws);
    f16* w16      = (f16*)(ws + 26542080);     // 2,359,296 B
    f16* w2_16    = (f16*)(ws + 28901376);     //    76,800 B
    float* bnscale = (float*)(ws + 28978176);  //     2,048 B
    float* bnshift = (float*)(ws + 28980224);  //     2,048 B
    f16* y16      = (f16*)(ws + 28982272);     // 44,302,336 B (total ~73.3 MB)

    k_zero_border<<<NIMG * 8, 256, 0, stream>>>(x16p);
    k_prep_x<<<dim3(22, 8, NIMG), 256, 0, stream>>>(x, x16p);
    k_prep_w<<<4608, 256, 0, stream>>>(w1, w2, gamma, beta, mean, var,
                                       w16, w2_16, bnscale, bnshift);
    k_conv1<<<dim3(NIMG * NSPB, 2), 512, 0, stream>>>(x16p, w16, bnscale,
                                                      bnshift, y16);
    k_conv2<<<NIMG * 22, 256, 0, stream>>>(y16, w2_16, b2, out);
}

// Round 10
// 159.985 us; speedup vs baseline: 1.9591x; 1.9591x over previous
//
#include <hip/hip_runtime.h>

typedef _Float16 f16;
typedef _Float16 f16x8 __attribute__((ext_vector_type(8)));
typedef _Float16 f16x4 __attribute__((ext_vector_type(4)));
typedef float f32x4 __attribute__((ext_vector_type(4)));

#define GDIM 52
#define GG 2704          // 52*52
#define CIN 256
#define CMID 512
#define COUT 75
#define NIMG 16
#define SPT 192          // conv1 spatial tile
#define NSPB 15          // ceil(2704/192)
#define PH 60            // padded rows in x16p
#define PW 54            // padded cols

#define SLAB_SZ 24576    // one slab buffer (7 rows x 54 cols x 32ci f16, 384-pix slots)

#define VMCNT0 asm volatile("s_waitcnt vmcnt(0)" ::: "memory")
#define SB0 __builtin_amdgcn_sched_barrier(0)

__device__ __forceinline__ float sigmoidf_(float x) {
    return 1.0f / (1.0f + __expf(-x));
}

__device__ __forceinline__ void gload16(const void* g, void* l) {
    __builtin_amdgcn_global_load_lds(
        (const __attribute__((address_space(1))) unsigned int*)g,
        (__attribute__((address_space(3))) unsigned int*)l, 16, 0, 0);
}

// ---- zero the pad borders of x16p (rows 0,53..59 fully; cols 0,53 rows 1..52) ----
__global__ __launch_bounds__(256) void k_zero_border(f16* __restrict__ x16p) {
    int ic = blockIdx.x;             // img*8 + ck
    int tid = threadIdx.x;
    f16x8 z;
#pragma unroll
    for (int k = 0; k < 8; ++k) z[k] = (f16)0;
    for (int j = tid; j < 536; j += 256) {
        int row, col;
        if (j < 432) { int r = j / 54; row = (r == 0) ? 0 : 52 + r; col = j % 54; }
        else { int k = j - 432; row = 1 + (k >> 1); col = (k & 1) * 53; }
        f16* p = x16p + (((size_t)ic * PH + row) * PW + col) * 32;
#pragma unroll
        for (int q = 0; q < 4; ++q) *(f16x8*)(p + q * 8) = z;
    }
}

// ---- prep: x [img][ci][hw] f32 -> x16p [img][ck][h+1][w+1][32ci] f16 (padded) ----
__global__ __launch_bounds__(256) void k_prep_x(const float* __restrict__ x,
                                                f16* __restrict__ x16p) {
    __shared__ float ls[32][133];
    int hw0 = blockIdx.x * 128, ck = blockIdx.y, img = blockIdx.z;
    int tid = threadIdx.x;
    const float* xb = x + ((size_t)img * CIN + ck * 32) * GG;
#pragma unroll
    for (int i = 0; i < 16; ++i) {
        int idx = tid + i * 256;
        int r = idx >> 7, c = idx & 127;
        int hw = hw0 + c;
        ls[r][c] = (hw < GG) ? xb[(size_t)r * GG + hw] : 0.0f;
    }
    __syncthreads();
    int col = tid >> 1, half = tid & 1;
    int hw = hw0 + col;
    if (hw < GG) {
        int h = hw / GDIM, w = hw % GDIM;
        f16* dst = x16p + ((((size_t)img * 8 + ck) * PH + h + 1) * PW + (w + 1)) * 32 + half * 16;
        f16x8 o0, o1;
#pragma unroll
        for (int j = 0; j < 8; ++j) o0[j] = (f16)ls[half * 16 + j][col];
#pragma unroll
        for (int j = 0; j < 8; ++j) o1[j] = (f16)ls[half * 16 + 8 + j][col];
        *(f16x8*)dst = o0;
        *(f16x8*)(dst + 8) = o1;
    }
}

// ---- prep: weights + BN fold.  w16 layout [tap][ck][co][32ci] ----
__global__ __launch_bounds__(256) void k_prep_w(
    const float* __restrict__ w1, const float* __restrict__ w2,
    const float* __restrict__ gamma, const float* __restrict__ beta,
    const float* __restrict__ mean, const float* __restrict__ var,
    f16* __restrict__ w16, f16* __restrict__ w2_16,
    float* __restrict__ bnscale, float* __restrict__ bnshift) {
    int i = blockIdx.x * 256 + threadIdx.x;   // exactly 9*8*512*32 = 1,179,648 threads
    int cl = i & 31;
    int co = (i >> 5) & 511;
    int ckt = i >> 14;          // tap*8 + ck
    int ck = ckt & 7, tap = ckt >> 3;
    int ci = ck * 32 + cl;
    w16[i] = (f16)w1[(size_t)co * 2304 + ci * 9 + tap];
    if (i < COUT * CMID) w2_16[i] = (f16)w2[i];
    if (i < CMID) {
        float s = gamma[i] * rsqrtf(var[i] + 1e-5f);
        bnscale[i] = s;
        bnshift[i] = beta[i] - mean[i] * s;
    }
}

// tap pixel delta (f16 units) for tap literal T
#define TPX(T) ((((T) / 3 - 1) * PW + ((T) % 3) - 1) * 8)

// ---- conv1: 3x3 + BN + LeakyReLU -> y16 [half][img][n][256co] ----
// 512 thr / 8 waves (4 wm x 2 wn); block 256co x 192sp; wave 64co x 96sp.
// A-frags: global->register AT USE (L1/L2-hot weights; no cross-tap reg state).
// B-frags: LDS slab (DMA-staged, double-buffered per ck).
// ONE barrier+vmcnt(0) per ck (9-tap prefetch distance -> free). Waves drift
// within a ck so MFMA overlaps the other wave's loads. SB0 per tap stops
// cross-tap load hoisting (the R6/R7/R9 spill trap).
__global__ __launch_bounds__(512, 2) void k_conv1(
    const f16* __restrict__ x16p, const f16* __restrict__ w16,
    const float* __restrict__ bnscale, const float* __restrict__ bnshift,
    f16* __restrict__ y16) {
    __shared__ __align__(16) char smem[101376];   // slab dbuf 49152 / epilogue tb
    int img = blockIdx.x / NSPB, sb = blockIdx.x % NSPB;
    int n0 = sb * SPT;
    int h_lo = n0 / GDIM;
    int half = blockIdx.y;
    int co0 = half * 256;
    int tid = threadIdx.x;
    int lane = tid & 63, wave = tid >> 6;
    int wm = wave >> 1, wn = wave & 1;
    int l15 = lane & 15, kg = lane >> 4;
    int kgx = kg * 3072;                            // f16 units: kg slot in slab

    int roff[6];
#pragma unroll
    for (int nf = 0; nf < 6; ++nf) {
        int n = n0 + wn * 96 + nf * 16 + l15;
        int nc = n < GG ? n : GG - 1;
        int hh = nc / GDIM, ww = nc % GDIM;
        roff[nf] = ((hh - h_lo + 1) * PW + (ww + 1)) * 8;
    }

    f32x4 acc[4][6];
#pragma unroll
    for (int a = 0; a < 4; ++a)
#pragma unroll
        for (int b = 0; b < 6; ++b) {
            acc[a][b][0] = 0.f; acc[a][b][1] = 0.f;
            acc[a][b][2] = 0.f; acc[a][b][3] = 0.f;
        }

    const f16* xbase = x16p + ((size_t)img * 8 * PH + h_lo) * (PW * 32);
    const f16* wAfrag = w16 + (size_t)co0 * 32 + (wm * 64 + l15) * 32 + kg * 8;

    // ---- prologue: issue slab(0) DMA ----
    {
        f16* sd = (f16*)smem;
#pragma unroll
        for (int p = 0; p < 3; ++p) {
            int c = p * 512 + tid;
            int s = c / 384, pix = c % 384;
            gload16(xbase + (size_t)pix * 32 + s * 8, sd + (size_t)c * 8);
        }
    }

    for (int ck = 0; ck < 8; ++ck) {
        VMCNT0;                       // slab(ck) DMA done (issued a full ck ago)
        __builtin_amdgcn_s_barrier();
        SB0;
        if (ck < 7) {                 // issue slab(ck+1) into the other buffer
            const f16* sg = xbase + (size_t)(ck + 1) * (PH * PW * 32);
            f16* sd = (f16*)(smem + ((ck + 1) & 1) * SLAB_SZ);
#pragma unroll
            for (int p = 0; p < 3; ++p) {
                int c = p * 512 + tid;
                int s = c / 384, pix = c % 384;
                gload16(sg + (size_t)pix * 32 + s * 8, sd + (size_t)c * 8);
            }
        }
        SB0;
        const f16* Sb = (const f16*)(smem + (ck & 1) * SLAB_SZ);
#pragma unroll
        for (int tap = 0; tap < 9; ++tap) {
            // B-frags from LDS (contiguous 1 KB wave runs)
            const f16* bp = Sb + kgx + TPX(tap);
            f16x8 b0 = *(const f16x8*)(bp + roff[0]);
            f16x8 b1 = *(const f16x8*)(bp + roff[1]);
            f16x8 b2 = *(const f16x8*)(bp + roff[2]);
            f16x8 b3 = *(const f16x8*)(bp + roff[3]);
            f16x8 b4 = *(const f16x8*)(bp + roff[4]);
            f16x8 b5 = *(const f16x8*)(bp + roff[5]);
            // A-frags from global (L1/L2-hot), used immediately
            const f16* ap = wAfrag + (size_t)(tap * 8 + ck) * 16384;
            f16x8 a0 = *(const f16x8*)(ap);
            f16x8 a1 = *(const f16x8*)(ap + 512);
            f16x8 a2 = *(const f16x8*)(ap + 1024);
            f16x8 a3 = *(const f16x8*)(ap + 1536);
            __builtin_amdgcn_s_setprio(1);
#pragma unroll
            for (int nf = 0; nf < 6; ++nf) {
                f16x8 bf = nf == 0 ? b0 : nf == 1 ? b1 : nf == 2 ? b2
                         : nf == 3 ? b3 : nf == 4 ? b4 : b5;
                acc[0][nf] = __builtin_amdgcn_mfma_f32_16x16x32_f16(a0, bf, acc[0][nf], 0, 0, 0);
                acc[1][nf] = __builtin_amdgcn_mfma_f32_16x16x32_f16(a1, bf, acc[1][nf], 0, 0, 0);
                acc[2][nf] = __builtin_amdgcn_mfma_f32_16x16x32_f16(a2, bf, acc[2][nf], 0, 0, 0);
                acc[3][nf] = __builtin_amdgcn_mfma_f32_16x16x32_f16(a3, bf, acc[3][nf], 0, 0, 0);
            }
            __builtin_amdgcn_s_setprio(0);
            SB0;
        }
    }
    // ---- epilogue: BN + leaky -> LDS transpose (stride 264 f16) -> linear y16 ----
    VMCNT0;
    __syncthreads();
    f16* tb = (f16*)smem;
#pragma unroll
    for (int mf = 0; mf < 4; ++mf) {
        int cr = wm * 64 + mf * 16 + kg * 4;
        f32x4 sc = *(const f32x4*)(bnscale + co0 + cr);
        f32x4 sh = *(const f32x4*)(bnshift + co0 + cr);
#pragma unroll
        for (int nf = 0; nf < 6; ++nf) {
            int pl = wn * 96 + nf * 16 + l15;
            f16x4 o;
#pragma unroll
            for (int i = 0; i < 4; ++i) {
                float v = acc[mf][nf][i] * sc[i] + sh[i];
                o[i] = (f16)(v > 0.f ? v : 0.1f * v);
            }
            *(f16x4*)(tb + pl * 264 + cr) = o;
        }
    }
    __syncthreads();
    int valid = GG - n0; if (valid > SPT) valid = SPT;
    f16* yb = y16 + (size_t)half * (NIMG * (size_t)GG * 256) + ((size_t)img * GG + n0) * 256;
#pragma unroll
    for (int p = 0; p < 12; ++p) {
        int u = p * 512 + tid, pl = u >> 5, slot = u & 31;
        if (pl < valid)
            *(f16x8*)(yb + (size_t)pl * 256 + slot * 8) =
                *(const f16x8*)(tb + pl * 264 + slot * 8);
    }
}

// ---- conv2 (1x1, K=512) + bias + YOLO decode. 256 thr / 4 waves, 128 n per block ----
__global__ __launch_bounds__(256) void k_conv2(
    const f16* __restrict__ y16, const f16* __restrict__ w2_16,
    const float* __restrict__ b2, float* __restrict__ out) {
    __shared__ float ct[128][81];   // 41472 B
    int img = blockIdx.x / 22, nb = blockIdx.x % 22;
    int n0 = nb * 128;
    int tid = threadIdx.x;
    int lane = tid & 63, wave = tid >> 6;
    int l15 = lane & 15, kg = lane >> 4;

    f32x4 acc[5][2];
#pragma unroll
    for (int a = 0; a < 5; ++a)
#pragma unroll
        for (int b = 0; b < 2; ++b) {
            acc[a][b][0] = 0.f; acc[a][b][1] = 0.f;
            acc[a][b][2] = 0.f; acc[a][b][3] = 0.f;
        }

    int nn[2];
#pragma unroll
    for (int nf = 0; nf < 2; ++nf) {
        int n = n0 + wave * 32 + nf * 16 + l15;
        nn[nf] = n < GG ? n : GG - 1;
    }
    for (int c0 = 0; c0 < CMID; c0 += 32) {
        const f16* yb = y16 + (size_t)(c0 >> 8) * (NIMG * (size_t)GG * 256) +
                        (size_t)img * GG * 256;
        int c = c0 & 255;
        f16x8 af[5];
#pragma unroll
        for (int mf = 0; mf < 5; ++mf) {
            int co = mf * 16 + l15;
            if (co < COUT)
                af[mf] = *(const f16x8*)(w2_16 + (size_t)co * CMID + c0 + kg * 8);
            else {
#pragma unroll
                for (int k = 0; k < 8; ++k) af[mf][k] = (f16)0;
            }
        }
#pragma unroll
        for (int nf = 0; nf < 2; ++nf) {
            f16x8 bf = *(const f16x8*)(yb + (size_t)nn[nf] * 256 + c + kg * 8);
#pragma unroll
            for (int mf = 0; mf < 5; ++mf)
                acc[mf][nf] = __builtin_amdgcn_mfma_f32_16x16x32_f16(
                    af[mf], bf, acc[mf][nf], 0, 0, 0);
        }
    }
#pragma unroll
    for (int mf = 0; mf < 5; ++mf)
#pragma unroll
        for (int nf = 0; nf < 2; ++nf)
            *(f32x4*)(&ct[wave * 32 + nf * 16 + l15][mf * 16 + kg * 4]) = acc[mf][nf];
    __syncthreads();
    // decode: 384 (anchor, n) items over 256 threads
    for (int j = tid; j < 384; j += 256) {
        int a = j >> 7, nl = j & 127;
        int n = n0 + nl;
        if (n >= GG) continue;
        const float* t = &ct[nl][a * 25];
        float tv[25];
#pragma unroll
        for (int q = 0; q < 25; ++q) tv[q] = t[q] + b2[a * 25 + q];
        int h = n / GDIM, w = n % GDIM;
        const float AW[3] = {10.f, 16.f, 33.f};
        const float AH[3] = {13.f, 30.f, 23.f};
        float bx = (sigmoidf_(tv[0]) + (float)w) * 8.0f;
        float by = (sigmoidf_(tv[1]) + (float)h) * 8.0f;
        float bw_ = __expf(tv[2]) * AW[a];
        float bh_ = __expf(tv[3]) * AH[a];
        float* o = out + ((size_t)img * 8112 + (size_t)a * GG + n) * 25;
        o[0] = bx; o[1] = by; o[2] = bw_; o[3] = bh_;
        o[4] = sigmoidf_(tv[4]);
#pragma unroll
        for (int q = 0; q < 20; ++q) o[5 + q] = sigmoidf_(tv[5 + q]);
    }
}

extern "C" void kernel_launch(void* const* d_in, const int* in_sizes, int n_in,
                              void* d_out, int out_size, void* d_ws, size_t ws_size,
                              hipStream_t stream) {
    (void)in_sizes; (void)n_in; (void)out_size; (void)ws_size;
    const float* x     = (const float*)d_in[0];
    const float* w1    = (const float*)d_in[1];
    const float* gamma = (const float*)d_in[2];
    const float* beta  = (const float*)d_in[3];
    const float* mean  = (const float*)d_in[4];
    const float* var   = (const float*)d_in[5];
    const float* w2    = (const float*)d_in[6];
    const float* b2    = (const float*)d_in[7];
    float* out = (float*)d_out;

    char* ws = (char*)d_ws;
    // x16p: 16*8*60*54*32*2 = 26,542,080 B
    f16* x16p     = (f16*)(ws);
    f16* w16      = (f16*)(ws + 26542080);     // 2,359,296 B
    f16* w2_16    = (f16*)(ws + 28901376);     //    76,800 B
    float* bnscale = (float*)(ws + 28978176);  //     2,048 B
    float* bnshift = (float*)(ws + 28980224);  //     2,048 B
    f16* y16      = (f16*)(ws + 28982272);     // 44,302,336 B (total ~73.3 MB)

    k_zero_border<<<NIMG * 8, 256, 0, stream>>>(x16p);
    k_prep_x<<<dim3(22, 8, NIMG), 256, 0, stream>>>(x, x16p);
    k_prep_w<<<4608, 256, 0, stream>>>(w1, w2, gamma, beta, mean, var,
                                       w16, w2_16, bnscale, bnshift);
    k_conv1<<<dim3(NIMG * NSPB, 2), 512, 0, stream>>>(x16p, w16, bnscale,
                                                      bnshift, y16);
    k_conv2<<<NIMG * 22, 256, 0, stream>>>(y16, w2_16, b2, out);
}